// Round 1
// baseline (2786.803 us; speedup 1.0000x reference)
//
#include <hip/hip_runtime.h>
#include <hip/hip_bf16.h>

#define D_MODEL 1024
#define NHEAD 16
#define HEAD_DIM 64
#define SEQ 1024
#define BATCH 4
#define TQ 8

__device__ __forceinline__ float sigmoidf_(float x) {
  return 1.0f / (1.0f + __expf(-x));
}

// C[M=4096, N=1024] = A[4096,1024] @ W[1024,1024] + bias
// mode 0: write out[((h*B + b)*SEQ + s)*64 + d]  (h=n>>6, d=n&63, s=m>>2, b=m&3)
// mode 1: write out[m*1024 + n]
__global__ __launch_bounds__(256) void gemm_k(
    const float* __restrict__ A, const float* __restrict__ W,
    const float* __restrict__ bias, float* __restrict__ out, int mode)
{
  __shared__ float A_s[16][128];   // [k][m] transposed
  __shared__ float B_s[16][128];   // [k][n]
  const int tid = threadIdx.x;
  const int m0 = blockIdx.y * 128;
  const int n0 = blockIdx.x * 128;
  const int tx = tid & 15, ty = tid >> 4;
  const int am = tid & 127, akq = tid >> 7;   // A loader: row am, k-quads akq, akq+2
  const int bkr = tid >> 4, bnq = tid & 15;   // B loader: k-row bkr, n-quads bnq, bnq+16
  float acc[8][8];
  #pragma unroll
  for (int i = 0; i < 8; ++i)
    #pragma unroll
    for (int j = 0; j < 8; ++j) acc[i][j] = 0.f;

  for (int kt = 0; kt < D_MODEL; kt += 16) {
    #pragma unroll
    for (int i = 0; i < 2; ++i) {
      int kq = akq + 2 * i;
      float4 av = *(const float4*)(A + (size_t)(m0 + am) * D_MODEL + kt + kq * 4);
      A_s[kq * 4 + 0][am] = av.x;
      A_s[kq * 4 + 1][am] = av.y;
      A_s[kq * 4 + 2][am] = av.z;
      A_s[kq * 4 + 3][am] = av.w;
    }
    #pragma unroll
    for (int i = 0; i < 2; ++i) {
      int nq = bnq + 16 * i;
      *(float4*)&B_s[bkr][nq * 4] =
          *(const float4*)(W + (size_t)(kt + bkr) * D_MODEL + n0 + nq * 4);
    }
    __syncthreads();
    #pragma unroll
    for (int k = 0; k < 16; ++k) {
      float a[8], bb[8];
      *(float4*)&a[0]  = *(float4*)&A_s[k][ty * 8];
      *(float4*)&a[4]  = *(float4*)&A_s[k][ty * 8 + 4];
      *(float4*)&bb[0] = *(float4*)&B_s[k][tx * 8];
      *(float4*)&bb[4] = *(float4*)&B_s[k][tx * 8 + 4];
      #pragma unroll
      for (int i = 0; i < 8; ++i)
        #pragma unroll
        for (int j = 0; j < 8; ++j)
          acc[i][j] += a[i] * bb[j];
    }
    __syncthreads();
  }

  if (mode == 0) {
    #pragma unroll
    for (int i = 0; i < 8; ++i) {
      int gr = m0 + ty * 8 + i;
      int s = gr >> 2, b = gr & 3;
      #pragma unroll
      for (int j = 0; j < 8; ++j) {
        int gc = n0 + tx * 8 + j;
        int h = gc >> 6, d = gc & 63;
        out[(size_t)((h * BATCH + b) * SEQ + s) * HEAD_DIM + d] = acc[i][j] + bias[gc];
      }
    }
  } else {
    #pragma unroll
    for (int i = 0; i < 8; ++i) {
      int gr = m0 + ty * 8 + i;
      #pragma unroll
      for (int j = 0; j < 8; ++j) {
        int gc = n0 + tx * 8 + j;
        out[(size_t)gr * D_MODEL + gc] = acc[i][j] + bias[gc];
      }
    }
  }
}

// One block per (hb, 8-query tile). Fused scores + CoPE + softmax + PV.
__global__ __launch_bounds__(256) void attn_k(
    const float* __restrict__ qb, const float* __restrict__ kb,
    const float* __restrict__ vb, const float* __restrict__ pe,
    float* __restrict__ att)
{
  __shared__ float q_s[TQ][HEAD_DIM];              // 2 KB
  __shared__ float S_s[TQ][SEQ];                   // 32 KB
  __shared__ __hip_bfloat16 li_s[TQ][1000];        // 15.6 KB
  __shared__ float v_s[32][64];                    // 8 KB
  __shared__ float red_s[8];
  __shared__ float qinv[TQ];

  const int tid = threadIdx.x;
  const int lane = tid & 63;
  const int wv = tid >> 6;
  const int hb = blockIdx.y;        // h*4 + b
  const int s0 = blockIdx.x * TQ;
  const float* Q = qb + (size_t)(hb * SEQ + s0) * HEAD_DIM;
  const float* K = kb + (size_t)hb * SEQ * HEAD_DIM;
  const float* V = vb + (size_t)hb * SEQ * HEAD_DIM;

  if (tid < TQ * HEAD_DIM / 4)
    ((float4*)q_s)[tid] = ((const float4*)Q)[tid];
  __syncthreads();

  const float scale = 0.125f;  // 1/sqrt(64)

  // ---- scores: S_s[q][t] = (q . k_t) * scale  (K read direct from global/L2)
  for (int pass = 0; pass < 4; ++pass) {
    int t = pass * 256 + tid;
    const float4* Kp = (const float4*)(K + (size_t)t * HEAD_DIM);
    float acc[TQ];
    #pragma unroll
    for (int q = 0; q < TQ; ++q) acc[q] = 0.f;
    #pragma unroll
    for (int jc = 0; jc < 16; ++jc) {
      float4 kk = Kp[jc];
      #pragma unroll
      for (int q = 0; q < TQ; ++q) {
        float4 qq = *(const float4*)&q_s[q][jc * 4];
        acc[q] += qq.x * kk.x + qq.y * kk.y + qq.z * kk.z + qq.w * kk.w;
      }
    }
    #pragma unroll
    for (int q = 0; q < TQ; ++q) S_s[q][t] = acc[q] * scale;
  }

  // ---- logits_int: li_s[q][n] = q . pos_emb[:,n]   (bf16 cache in LDS)
  #pragma unroll
  for (int i = 0; i < 4; ++i) {
    int n = tid + i * 256;
    if (n < 1000) {
      float acc[TQ];
      #pragma unroll
      for (int q = 0; q < TQ; ++q) acc[q] = 0.f;
      for (int j = 0; j < HEAD_DIM; ++j) {
        float p = pe[(size_t)j * 1000 + n];
        #pragma unroll
        for (int q = 0; q < TQ; ++q) acc[q] += q_s[q][j] * p;
      }
      #pragma unroll
      for (int q = 0; q < TQ; ++q) li_s[q][n] = __float2bfloat16(acc[q]);
    }
  }
  __syncthreads();

  // ---- per-query: reverse cumsum of gates, CoPE interp, softmax
  for (int q = 0; q < TQ; ++q) {
    float4 sv = *(float4*)&S_s[q][tid * 4];
    float g0 = sigmoidf_(sv.x), g1 = sigmoidf_(sv.y),
          g2 = sigmoidf_(sv.z), g3 = sigmoidf_(sv.w);
    float csum = g0 + g1 + g2 + g3;
    // wave-inclusive suffix scan of per-thread chunk sums
    float v = csum;
    #pragma unroll
    for (int off = 1; off < 64; off <<= 1) {
      float u = __shfl_down(v, off);
      v += (lane + off < 64) ? u : 0.f;
    }
    if (lane == 0) red_s[wv] = v;    // wave totals
    __syncthreads();
    float base = 0.f;
    #pragma unroll
    for (int w2 = 0; w2 < 4; ++w2)
      if (w2 > wv) base += red_s[w2];
    float after = base + (v - csum);   // sum of gates strictly after this chunk
    float p3 = after + g3;
    float p2 = p3 + g2;
    float p1 = p2 + g1;
    float p0 = p1 + g0;

    float sc4[4] = {sv.x, sv.y, sv.z, sv.w};
    float ps[4] = {p0, p1, p2, p3};
    float nl[4];
    float lmax = -1e30f;
    #pragma unroll
    for (int i = 0; i < 4; ++i) {
      float p = fminf(ps[i], 999.0f);
      float fl = floorf(p);
      int fi = (int)fl;
      int ci = (int)ceilf(p);
      float w = p - fl;
      float lf = __bfloat162float(li_s[q][fi]);
      float lc = __bfloat162float(li_s[q][ci]);
      nl[i] = sc4[i] + lc * w + lf * (1.f - w);
      lmax = fmaxf(lmax, nl[i]);
    }
    #pragma unroll
    for (int off = 32; off >= 1; off >>= 1)
      lmax = fmaxf(lmax, __shfl_xor(lmax, off));
    __syncthreads();                  // red_s (scan) reads complete
    if (lane == 0) red_s[wv] = lmax;
    __syncthreads();
    float bm = fmaxf(fmaxf(red_s[0], red_s[1]), fmaxf(red_s[2], red_s[3]));
    float e0 = __expf(nl[0] - bm), e1 = __expf(nl[1] - bm);
    float e2 = __expf(nl[2] - bm), e3 = __expf(nl[3] - bm);
    float4 ev; ev.x = e0; ev.y = e1; ev.z = e2; ev.w = e3;
    *(float4*)&S_s[q][tid * 4] = ev;
    float ssum = e0 + e1 + e2 + e3;
    #pragma unroll
    for (int off = 32; off >= 1; off >>= 1)
      ssum += __shfl_xor(ssum, off);
    __syncthreads();                  // bm reads complete
    if (lane == 0) red_s[wv] = ssum;
    __syncthreads();
    if (tid == 0) qinv[q] = 1.0f / (red_s[0] + red_s[1] + red_s[2] + red_s[3]);
    __syncthreads();
  }

  // ---- PV: out[q][d] = sum_t P[q][t] * V[t][d], V staged 32 rows at a time
  const int d = lane;
  const int qh = wv;                 // thread covers queries qh and qh+4
  float acc0 = 0.f, acc1 = 0.f;
  for (int ti = 0; ti < 32; ++ti) {
    #pragma unroll
    for (int i = 0; i < 2; ++i) {
      int idx = tid + i * 256;       // float4 index 0..511
      int row = idx >> 4, cq = idx & 15;
      *(float4*)&v_s[row][cq * 4] =
          *(const float4*)(V + (size_t)(ti * 32 + row) * HEAD_DIM + cq * 4);
    }
    __syncthreads();
    #pragma unroll
    for (int t = 0; t < 32; ++t) {
      float vv = v_s[t][d];
      acc0 += S_s[qh][ti * 32 + t] * vv;
      acc1 += S_s[qh + 4][ti * 32 + t] * vv;
    }
    __syncthreads();
  }
  const int h = hb >> 2, b = hb & 3;
  att[(size_t)((s0 + qh) * BATCH + b) * D_MODEL + h * HEAD_DIM + d] = acc0 * qinv[qh];
  att[(size_t)((s0 + qh + 4) * BATCH + b) * D_MODEL + h * HEAD_DIM + d] = acc1 * qinv[qh + 4];
}

extern "C" void kernel_launch(void* const* d_in, const int* in_sizes, int n_in,
                              void* d_out, int out_size, void* d_ws, size_t ws_size,
                              hipStream_t stream) {
  const float* x  = (const float*)d_in[0];
  const float* Wq = (const float*)d_in[1];
  const float* bq = (const float*)d_in[2];
  const float* Wk = (const float*)d_in[3];
  const float* bk = (const float*)d_in[4];
  const float* Wv = (const float*)d_in[5];
  const float* bv = (const float*)d_in[6];
  const float* Wo = (const float*)d_in[7];
  const float* bo = (const float*)d_in[8];
  const float* pe = (const float*)d_in[9];

  float* ws = (float*)d_ws;
  const size_t BUF = (size_t)NHEAD * BATCH * SEQ * HEAD_DIM;  // 4,194,304 floats
  float* qb = ws;
  float* kb = ws + BUF;
  float* vb = ws + 2 * BUF;
  float* ab = ws + 3 * BUF;

  dim3 gg(8, 32), gb(256);
  gemm_k<<<gg, gb, 0, stream>>>(x, Wq, bq, qb, 0);
  gemm_k<<<gg, gb, 0, stream>>>(x, Wk, bk, kb, 0);
  gemm_k<<<gg, gb, 0, stream>>>(x, Wv, bv, vb, 0);
  attn_k<<<dim3(SEQ / TQ, NHEAD * BATCH), gb, 0, stream>>>(qb, kb, vb, pe, ab);
  gemm_k<<<gg, gb, 0, stream>>>(ab, Wo, bo, (float*)d_out, 1);
}

// Round 2
// 979.902 us; speedup vs baseline: 2.8440x; 2.8440x over previous
//
#include <hip/hip_runtime.h>
#include <hip/hip_bf16.h>

#define D_MODEL 1024
#define NHEAD 16
#define HEAD_DIM 64
#define SEQ 1024
#define BATCH 4

typedef __attribute__((ext_vector_type(8))) short short8;
typedef __attribute__((ext_vector_type(4))) float f32x4;

__device__ __forceinline__ float sigmoidf_(float x) {
  return 1.0f / (1.0f + __expf(-x));
}
__device__ __forceinline__ short f2bf(float x) {
  union { float f; unsigned u; } v; v.f = x;
  unsigned r = v.u + 0x7fffu + ((v.u >> 16) & 1u);
  return (short)(r >> 16);
}
__device__ __forceinline__ float bf2f(unsigned short s) {
  union { unsigned u; float f; } v; v.u = ((unsigned)s) << 16; return v.f;
}
__device__ __forceinline__ short8 pack8(const float* p) {
  short8 r;
  #pragma unroll
  for (int j = 0; j < 8; ++j) r[j] = f2bf(p[j]);
  return r;
}

// ---------------- fp32 projection GEMM (unchanged, known-good) --------------
__global__ __launch_bounds__(256) void gemm_k(
    const float* __restrict__ A, const float* __restrict__ W,
    const float* __restrict__ bias, float* __restrict__ out, int mode)
{
  __shared__ float A_s[16][128];
  __shared__ float B_s[16][128];
  const int tid = threadIdx.x;
  const int m0 = blockIdx.y * 128;
  const int n0 = blockIdx.x * 128;
  const int tx = tid & 15, ty = tid >> 4;
  const int am = tid & 127, akq = tid >> 7;
  const int bkr = tid >> 4, bnq = tid & 15;
  float acc[8][8];
  #pragma unroll
  for (int i = 0; i < 8; ++i)
    #pragma unroll
    for (int j = 0; j < 8; ++j) acc[i][j] = 0.f;

  for (int kt = 0; kt < D_MODEL; kt += 16) {
    #pragma unroll
    for (int i = 0; i < 2; ++i) {
      int kq = akq + 2 * i;
      float4 av = *(const float4*)(A + (size_t)(m0 + am) * D_MODEL + kt + kq * 4);
      A_s[kq * 4 + 0][am] = av.x;
      A_s[kq * 4 + 1][am] = av.y;
      A_s[kq * 4 + 2][am] = av.z;
      A_s[kq * 4 + 3][am] = av.w;
    }
    #pragma unroll
    for (int i = 0; i < 2; ++i) {
      int nq = bnq + 16 * i;
      *(float4*)&B_s[bkr][nq * 4] =
          *(const float4*)(W + (size_t)(kt + bkr) * D_MODEL + n0 + nq * 4);
    }
    __syncthreads();
    #pragma unroll
    for (int k = 0; k < 16; ++k) {
      float a[8], bb[8];
      *(float4*)&a[0]  = *(float4*)&A_s[k][ty * 8];
      *(float4*)&a[4]  = *(float4*)&A_s[k][ty * 8 + 4];
      *(float4*)&bb[0] = *(float4*)&B_s[k][tx * 8];
      *(float4*)&bb[4] = *(float4*)&B_s[k][tx * 8 + 4];
      #pragma unroll
      for (int i = 0; i < 8; ++i)
        #pragma unroll
        for (int j = 0; j < 8; ++j)
          acc[i][j] += a[i] * bb[j];
    }
    __syncthreads();
  }

  if (mode == 0) {
    #pragma unroll
    for (int i = 0; i < 8; ++i) {
      int gr = m0 + ty * 8 + i;
      int s = gr >> 2, b = gr & 3;
      #pragma unroll
      for (int j = 0; j < 8; ++j) {
        int gc = n0 + tx * 8 + j;
        int h = gc >> 6, d = gc & 63;
        out[(size_t)((h * BATCH + b) * SEQ + s) * HEAD_DIM + d] = acc[i][j] + bias[gc];
      }
    }
  } else {
    #pragma unroll
    for (int i = 0; i < 8; ++i) {
      int gr = m0 + ty * 8 + i;
      #pragma unroll
      for (int j = 0; j < 8; ++j) {
        int gc = n0 + tx * 8 + j;
        out[(size_t)gr * D_MODEL + gc] = acc[i][j] + bias[gc];
      }
    }
  }
}

// ---------------- MFMA fused CoPE attention ---------------------------------
// Block: 16 queries of one (h,b). 256 threads = 4 waves.
// Wave w: scores for keys [256w,256w+256) and li for positions [256w,256w+256);
// then scan/softmax for queries [4w,4w+4) (wave-private, no barriers);
// then PV for output dims [16w,16w+16).
__global__ __launch_bounds__(256) void attn_k(
    const float* __restrict__ qb, const float* __restrict__ kb,
    const float* __restrict__ vb, const float* __restrict__ pe,
    float* __restrict__ att)
{
  __shared__ unsigned short S_s[16][1032];   // scores then P (bf16), pad 8
  __shared__ unsigned short li_s[16][1024];  // interp logits (bf16), 1000 used
  __shared__ float q_s[16][68];              // fp32 Q tile, padded
  __shared__ float qinv_s[16];

  const int tid = threadIdx.x;
  const int lane = tid & 63;
  const int wv = tid >> 6;
  const int col = lane & 15;   // m/n index inside 16x16 tile
  const int quad = lane >> 4;  // 0..3
  const int hb = blockIdx.y;
  const int s0 = blockIdx.x * 16;

  const float* Q = qb + ((size_t)hb * SEQ + s0) * HEAD_DIM;
  const float* K = kb + (size_t)hb * SEQ * HEAD_DIM;
  const float* V = vb + (size_t)hb * SEQ * HEAD_DIM;

  // ---- load Q tile (16x64) coalesced
  {
    int row = tid >> 4, c4 = tid & 15;
    float4 qv = *(const float4*)(Q + row * HEAD_DIM + c4 * 4);
    *(float4*)&q_s[row][c4 * 4] = qv;
  }
  __syncthreads();

  // ---- Q A-fragments (shared by scores and li), kept in registers
  short8 aq0 = pack8(&q_s[col][quad * 8]);
  short8 aq1 = pack8(&q_s[col][32 + quad * 8]);

  // ---- Phase A: scores S[16 q][1024 t] = (Q K^T) * scale, bf16 into LDS
  #pragma unroll 2
  for (int kt = 0; kt < 16; ++kt) {
    int t0 = wv * 256 + kt * 16;
    const float* Kr = K + (size_t)(t0 + col) * HEAD_DIM;
    short8 b0 = pack8(Kr + quad * 8);
    short8 b1 = pack8(Kr + 32 + quad * 8);
    f32x4 sc = {0.f, 0.f, 0.f, 0.f};
    sc = __builtin_amdgcn_mfma_f32_16x16x32_bf16(aq0, b0, sc, 0, 0, 0);
    sc = __builtin_amdgcn_mfma_f32_16x16x32_bf16(aq1, b1, sc, 0, 0, 0);
    #pragma unroll
    for (int r = 0; r < 4; ++r)
      S_s[quad * 4 + r][t0 + col] = (unsigned short)f2bf(sc[r] * 0.125f);
  }

  // ---- Phase B: li[16 q][1000 n] = Q @ pos_emb, bf16 into LDS
  #pragma unroll 2
  for (int nt = 0; nt < 16; ++nt) {
    int n0 = wv * 256 + nt * 16;
    int n = n0 + col;
    bool ok = (n < 1000);
    short8 b0, b1;
    #pragma unroll
    for (int j = 0; j < 8; ++j) {
      float p0 = ok ? pe[(size_t)(quad * 8 + j) * 1000 + n] : 0.f;
      float p1 = ok ? pe[(size_t)(32 + quad * 8 + j) * 1000 + n] : 0.f;
      b0[j] = f2bf(p0);
      b1[j] = f2bf(p1);
    }
    f32x4 li = {0.f, 0.f, 0.f, 0.f};
    li = __builtin_amdgcn_mfma_f32_16x16x32_bf16(aq0, b0, li, 0, 0, 0);
    li = __builtin_amdgcn_mfma_f32_16x16x32_bf16(aq1, b1, li, 0, 0, 0);
    #pragma unroll
    for (int r = 0; r < 4; ++r)
      li_s[quad * 4 + r][n] = (unsigned short)f2bf(li[r]);
  }
  __syncthreads();

  // ---- Phase C: wave-private scan + CoPE + softmax for queries 4w..4w+3
  #pragma unroll 1
  for (int i = 0; i < 4; ++i) {
    int q = wv * 4 + i;
    const unsigned short* Sp = &S_s[q][lane * 16];
    float s[16], suf[16];
    #pragma unroll
    for (int j = 0; j < 16; ++j) s[j] = bf2f(Sp[j]);
    float run = 0.f;
    #pragma unroll
    for (int j = 15; j >= 0; --j) {
      run += sigmoidf_(s[j]);
      suf[j] = run;
    }
    // wave suffix scan of chunk totals
    float v = run;
    #pragma unroll
    for (int off = 1; off < 64; off <<= 1) {
      float u = __shfl_down(v, off);
      v += (lane + off < 64) ? u : 0.f;
    }
    float after = v - run;  // sum of gates strictly after this 16-chunk
    float lg[16];
    float m = -1e30f;
    #pragma unroll
    for (int j = 0; j < 16; ++j) {
      float p = fminf(after + suf[j], 999.0f);
      float fl = floorf(p);
      int fi = (int)fl;
      int ci = (int)ceilf(p);
      float w = p - fl;
      float lf = bf2f(li_s[q][fi]);
      float lc = bf2f(li_s[q][ci]);
      lg[j] = s[j] + lc * w + lf * (1.f - w);
      m = fmaxf(m, lg[j]);
    }
    #pragma unroll
    for (int off = 1; off < 64; off <<= 1) m = fmaxf(m, __shfl_xor(m, off));
    float rs = 0.f;
    unsigned short pb[16];
    #pragma unroll
    for (int j = 0; j < 16; ++j) {
      float e = __expf(lg[j] - m);
      rs += e;
      pb[j] = (unsigned short)f2bf(e);
    }
    #pragma unroll
    for (int off = 1; off < 64; off <<= 1) rs += __shfl_xor(rs, off);
    unsigned short* Pp = &S_s[q][lane * 16];
    #pragma unroll
    for (int j = 0; j < 16; ++j) Pp[j] = pb[j];
    if (lane == 0) qinv_s[q] = 1.0f / rs;
  }
  __syncthreads();

  // ---- Phase D: O[16 q][16 d] per wave = P @ V, P from LDS, V from global
  f32x4 o = {0.f, 0.f, 0.f, 0.f};
  const int d0 = wv * 16;
  #pragma unroll 4
  for (int kt = 0; kt < 32; ++kt) {
    int t0 = kt * 32;
    short8 a = *(const short8*)&S_s[col][t0 + quad * 8];
    short8 b;
    #pragma unroll
    for (int j = 0; j < 8; ++j)
      b[j] = f2bf(V[(size_t)(t0 + quad * 8 + j) * HEAD_DIM + d0 + col]);
    o = __builtin_amdgcn_mfma_f32_16x16x32_bf16(a, b, o, 0, 0, 0);
  }
  const int b_ = hb & 3, h = hb >> 2;
  #pragma unroll
  for (int r = 0; r < 4; ++r) {
    int q = quad * 4 + r;
    float val = o[r] * qinv_s[q];
    att[(size_t)((s0 + q) * BATCH + b_) * D_MODEL + h * HEAD_DIM + d0 + col] = val;
  }
}

extern "C" void kernel_launch(void* const* d_in, const int* in_sizes, int n_in,
                              void* d_out, int out_size, void* d_ws, size_t ws_size,
                              hipStream_t stream) {
  const float* x  = (const float*)d_in[0];
  const float* Wq = (const float*)d_in[1];
  const float* bq = (const float*)d_in[2];
  const float* Wk = (const float*)d_in[3];
  const float* bk = (const float*)d_in[4];
  const float* Wv = (const float*)d_in[5];
  const float* bv = (const float*)d_in[6];
  const float* Wo = (const float*)d_in[7];
  const float* bo = (const float*)d_in[8];
  const float* pe = (const float*)d_in[9];

  float* ws = (float*)d_ws;
  const size_t BUF = (size_t)NHEAD * BATCH * SEQ * HEAD_DIM;
  float* qb = ws;
  float* kb = ws + BUF;
  float* vb = ws + 2 * BUF;
  float* ab = ws + 3 * BUF;

  dim3 gg(8, 32), gb(256);
  gemm_k<<<gg, gb, 0, stream>>>(x, Wq, bq, qb, 0);
  gemm_k<<<gg, gb, 0, stream>>>(x, Wk, bk, kb, 0);
  gemm_k<<<gg, gb, 0, stream>>>(x, Wv, bv, vb, 0);
  attn_k<<<dim3(SEQ / 16, NHEAD * BATCH), gb, 0, stream>>>(qb, kb, vb, pe, ab);
  gemm_k<<<gg, gb, 0, stream>>>(ab, Wo, bo, (float*)d_out, 1);
}

// Round 3
// 502.666 us; speedup vs baseline: 5.5440x; 1.9494x over previous
//
#include <hip/hip_runtime.h>
#include <hip/hip_bf16.h>

#define D_MODEL 1024
#define NHEAD 16
#define HEAD_DIM 64
#define SEQ 1024
#define BATCH 4

typedef unsigned short us;
typedef __attribute__((ext_vector_type(8))) short short8;
typedef __attribute__((ext_vector_type(4))) float f32x4;

#define MFMA16 __builtin_amdgcn_mfma_f32_16x16x32_bf16

__device__ __forceinline__ float sigmoidf_(float x) {
  return 1.0f / (1.0f + __expf(-x));
}
__device__ __forceinline__ us f2bf(float x) {
  union { float f; unsigned u; } v; v.f = x;
  unsigned r = v.u + 0x7fffu + ((v.u >> 16) & 1u);
  return (us)(r >> 16);
}
__device__ __forceinline__ float bf2f(us s) {
  union { unsigned u; float f; } v; v.u = ((unsigned)s) << 16; return v.f;
}
__device__ __forceinline__ void split_bf(float v, us& h, us& l) {
  h = f2bf(v);
  l = f2bf(v - bf2f(h));
}
__device__ __forceinline__ void async16(us* lds, const us* g) {
  __builtin_amdgcn_global_load_lds(
      (const __attribute__((address_space(1))) unsigned int*)(const void*)g,
      (__attribute__((address_space(3))) unsigned int*)(void*)lds, 16, 0, 0);
}

// ---------------- prep: bf16 convert / transpose -----------------------------
// jobs: [0,2048): x -> xh,xl   [2048,6144): W transpose  [6144,6208): pe^T
__global__ __launch_bounds__(256) void prep_k(
    const float* __restrict__ x, const float* __restrict__ Wq,
    const float* __restrict__ Wk, const float* __restrict__ Wv,
    const float* __restrict__ Wo, const float* __restrict__ pe,
    us* __restrict__ xh, us* __restrict__ xl, us* __restrict__ wqk,
    us* __restrict__ wvh, us* __restrict__ wvl, us* __restrict__ woh,
    us* __restrict__ wol, us* __restrict__ pet)
{
  __shared__ float tile[32][33];
  const int bid = blockIdx.x, tid = threadIdx.x;
  if (bid < 2048) {
    int i0 = bid * 2048 + tid * 8;
    float4 v0 = *(const float4*)(x + i0);
    float4 v1 = *(const float4*)(x + i0 + 4);
    float vv[8] = {v0.x, v0.y, v0.z, v0.w, v1.x, v1.y, v1.z, v1.w};
    short8 hh, ll;
    #pragma unroll
    for (int j = 0; j < 8; ++j) {
      us h, l; split_bf(vv[j], h, l);
      hh[j] = (short)h; ll[j] = (short)l;
    }
    *(short8*)(xh + i0) = hh;
    *(short8*)(xl + i0) = ll;
  } else if (bid < 6144) {
    int wj = bid - 2048;
    int w = wj >> 10, t = wj & 1023;
    int k0 = (t >> 5) * 32, n0 = (t & 31) * 32;
    const float* W = (w == 0) ? Wq : (w == 1) ? Wk : (w == 2) ? Wv : Wo;
    int tx = tid & 31, ty = tid >> 5;
    #pragma unroll
    for (int rep = 0; rep < 4; ++rep) {
      int ky = ty * 4 + rep;
      tile[ky][tx] = W[(size_t)(k0 + ky) * 1024 + n0 + tx];
    }
    __syncthreads();
    #pragma unroll
    for (int rep = 0; rep < 4; ++rep) {
      int ny = ty * 4 + rep;
      float v = tile[tx][ny];            // = W[k0+tx][n0+ny]
      int n = n0 + ny, k = k0 + tx;
      if (w < 2) {
        wqk[(size_t)(w * 1024 + n) * 1024 + k] = f2bf(v);
      } else {
        us h, l; split_bf(v, h, l);
        us* dh = (w == 2) ? wvh : woh;
        us* dl = (w == 2) ? wvl : wol;
        dh[(size_t)n * 1024 + k] = h;
        dl[(size_t)n * 1024 + k] = l;
      }
    }
  } else {
    int pj = bid - 6144;
    int k0 = (pj & 1) * 32, n0 = (pj >> 1) * 32;
    int tx = tid & 31, ty = tid >> 5;
    #pragma unroll
    for (int rep = 0; rep < 4; ++rep) {
      int ky = ty * 4 + rep;
      tile[ky][tx] = (n0 + tx < 1000) ? pe[(size_t)(k0 + ky) * 1000 + n0 + tx] : 0.f;
    }
    __syncthreads();
    #pragma unroll
    for (int rep = 0; rep < 4; ++rep) {
      int ny = ty * 4 + rep;
      int n = n0 + ny;
      if (n < 1000) pet[(size_t)n * 64 + k0 + tx] = f2bf(tile[tx][ny]);
    }
  }
}

// ---------------- bf16 MFMA GEMM, m97-style ---------------------------------
// C[4096, N] = A[4096,1024] . Bt[N,1024]^T  (both bf16 K-contiguous)
// TERMS=1: plain.  TERMS=3: A=(A0+A1), B=(B0+B1), acc = A0B0 + A0B1 + A1B0.
// mode 0: bf16 scatter to qb/kb   mode 1: hi/lo bf16 to vt[h|l] (transposed)
// mode 2: fp32 row-major
template<int TERMS, int TN>
__global__ __launch_bounds__(256) void mgemm(
    const us* __restrict__ A0, const us* __restrict__ A1,
    const us* __restrict__ B0, const us* __restrict__ B1,
    const float* __restrict__ bias0, const float* __restrict__ bias1,
    void* out0, void* out1, int mode)
{
  constexpr int PA = (TERMS == 3) ? 2 : 1;
  constexpr int NJ = TN / 32;          // n-frags per wave
  constexpr int NW = TN / 2;           // n-span per wave
  __shared__ us As[PA][128][32];
  __shared__ us Bs[PA][TN][32];
  const int tid = threadIdx.x, ln = tid & 63, wv = tid >> 6;
  const int col = ln & 15, quad = ln >> 4;
  const int wr = wv >> 1, wc = wv & 1;
  const int m0 = blockIdx.y * 128, n0 = blockIdx.x * TN;
  const us* Ap[2] = {A0, A1};
  const us* Bp[2] = {B0, B1};

  f32x4 acc[4][NJ];
  #pragma unroll
  for (int i = 0; i < 4; ++i)
    #pragma unroll
    for (int j = 0; j < NJ; ++j) acc[i][j] = (f32x4){0.f, 0.f, 0.f, 0.f};

  for (int kt = 0; kt < 1024; kt += 32) {
    // stage A (512 16B chunks per plane), XOR-swizzled k-chunks
    #pragma unroll
    for (int p = 0; p < PA; ++p)
      #pragma unroll
      for (int j = 0; j < 2; ++j) {
        int c = j * 256 + wv * 64 + ln;
        int m = c >> 2;
        int kq = (c & 3) ^ ((c >> 3) & 3);
        async16((us*)&As[p][0][0] + (size_t)(j * 256 + wv * 64) * 8,
                Ap[p] + (size_t)(m0 + m) * 1024 + kt + kq * 8);
      }
    // stage B (TN*4 chunks per plane)
    #pragma unroll
    for (int p = 0; p < PA; ++p)
      #pragma unroll
      for (int j = 0; j < TN / 64; ++j) {
        int c = j * 256 + wv * 64 + ln;
        int n = c >> 2;
        int kq = (c & 3) ^ ((c >> 3) & 3);
        async16((us*)&Bs[p][0][0] + (size_t)(j * 256 + wv * 64) * 8,
                Bp[p] + (size_t)(n0 + n) * 1024 + kt + kq * 8);
      }
    __syncthreads();

    short8 a0[4], a1[4], b0[NJ], b1[NJ];
    #pragma unroll
    for (int i = 0; i < 4; ++i) {
      int r = wr * 64 + i * 16 + col;
      int q = quad ^ ((r >> 1) & 3);
      a0[i] = *(const short8*)&As[0][r][q * 8];
      if constexpr (TERMS == 3) a1[i] = *(const short8*)&As[1][r][q * 8];
    }
    #pragma unroll
    for (int j = 0; j < NJ; ++j) {
      int r = wc * NW + j * 16 + col;
      int q = quad ^ ((r >> 1) & 3);
      b0[j] = *(const short8*)&Bs[0][r][q * 8];
      if constexpr (TERMS == 3) b1[j] = *(const short8*)&Bs[1][r][q * 8];
    }
    #pragma unroll
    for (int i = 0; i < 4; ++i)
      #pragma unroll
      for (int j = 0; j < NJ; ++j) {
        acc[i][j] = MFMA16(a0[i], b0[j], acc[i][j], 0, 0, 0);
        if constexpr (TERMS == 3) {
          acc[i][j] = MFMA16(a0[i], b1[j], acc[i][j], 0, 0, 0);
          acc[i][j] = MFMA16(a1[i], b0[j], acc[i][j], 0, 0, 0);
        }
      }
    __syncthreads();
  }

  // epilogue
  #pragma unroll
  for (int i = 0; i < 4; ++i)
    #pragma unroll
    for (int j = 0; j < NJ; ++j)
      #pragma unroll
      for (int r = 0; r < 4; ++r) {
        int grow = m0 + wr * 64 + i * 16 + quad * 4 + r;
        int gcol = n0 + wc * NW + j * 16 + col;
        float val = acc[i][j][r];
        if (mode == 0) {
          val += (gcol < 1024 ? bias0 : bias1)[gcol & 1023];
          int h = (gcol >> 6) & 15, d = gcol & 63, b = grow & 3, s = grow >> 2;
          ((us*)(gcol < 1024 ? out0 : out1))
              [(size_t)((h * 4 + b) * 1024 + s) * 64 + d] = f2bf(val);
        } else if (mode == 1) {
          val += bias0[gcol];
          int h = gcol >> 6, d = gcol & 63, b = grow & 3, s = grow >> 2;
          size_t idx = (size_t)((h * 4 + b) * 64 + d) * 1024 + s;
          us hh, ll; split_bf(val, hh, ll);
          ((us*)out0)[idx] = hh;
          ((us*)out1)[idx] = ll;
        } else {
          val += bias0[gcol];
          ((float*)out0)[(size_t)grow * 1024 + gcol] = val;
        }
      }
}

// ---------------- MFMA fused CoPE attention (all-bf16 inputs) ---------------
__global__ __launch_bounds__(256) void attn_k(
    const us* __restrict__ qb, const us* __restrict__ kb,
    const us* __restrict__ vth, const us* __restrict__ vtl,
    const us* __restrict__ pet, us* __restrict__ ah, us* __restrict__ al)
{
  __shared__ us S_s[16][1032];
  __shared__ us li_s[16][1024];
  __shared__ float qinv_s[16];

  const int tid = threadIdx.x;
  const int lane = tid & 63;
  const int wv = tid >> 6;
  const int col = lane & 15;
  const int quad = lane >> 4;
  const int hb = blockIdx.y;
  const int s0 = blockIdx.x * 16;

  const us* Q = qb + ((size_t)hb * SEQ + s0) * HEAD_DIM;
  const us* K = kb + (size_t)hb * SEQ * HEAD_DIM;
  const us* Vh = vth + (size_t)hb * HEAD_DIM * SEQ;
  const us* Vl = vtl + (size_t)hb * HEAD_DIM * SEQ;

  short8 aq0 = *(const short8*)(Q + col * 64 + quad * 8);
  short8 aq1 = *(const short8*)(Q + col * 64 + 32 + quad * 8);

  // ---- Phase A: scores
  #pragma unroll 2
  for (int kt = 0; kt < 16; ++kt) {
    int t0 = wv * 256 + kt * 16;
    const us* Kr = K + (size_t)(t0 + col) * 64;
    short8 b0 = *(const short8*)(Kr + quad * 8);
    short8 b1 = *(const short8*)(Kr + 32 + quad * 8);
    f32x4 sc = {0.f, 0.f, 0.f, 0.f};
    sc = MFMA16(aq0, b0, sc, 0, 0, 0);
    sc = MFMA16(aq1, b1, sc, 0, 0, 0);
    #pragma unroll
    for (int r = 0; r < 4; ++r)
      S_s[quad * 4 + r][t0 + col] = f2bf(sc[r] * 0.125f);
  }

  // ---- Phase B: interpolation logits
  #pragma unroll 2
  for (int nt = 0; nt < 16; ++nt) {
    int n = wv * 256 + nt * 16 + col;
    int nn = (n < 1000) ? n : 999;
    short8 b0 = *(const short8*)(pet + (size_t)nn * 64 + quad * 8);
    short8 b1 = *(const short8*)(pet + (size_t)nn * 64 + 32 + quad * 8);
    f32x4 li = {0.f, 0.f, 0.f, 0.f};
    li = MFMA16(aq0, b0, li, 0, 0, 0);
    li = MFMA16(aq1, b1, li, 0, 0, 0);
    #pragma unroll
    for (int r = 0; r < 4; ++r)
      li_s[quad * 4 + r][n] = f2bf(li[r]);
  }
  __syncthreads();

  // ---- Phase C: wave-private reverse cumsum + CoPE + softmax (4 q / wave)
  #pragma unroll 1
  for (int i = 0; i < 4; ++i) {
    int q = wv * 4 + i;
    const us* Sp = &S_s[q][lane * 16];
    float s[16], suf[16];
    #pragma unroll
    for (int j = 0; j < 16; ++j) s[j] = bf2f(Sp[j]);
    float run = 0.f;
    #pragma unroll
    for (int j = 15; j >= 0; --j) {
      run += sigmoidf_(s[j]);
      suf[j] = run;
    }
    float v = run;
    #pragma unroll
    for (int off = 1; off < 64; off <<= 1) {
      float u = __shfl_down(v, off);
      v += (lane + off < 64) ? u : 0.f;
    }
    float after = v - run;
    float lg[16];
    float m = -1e30f;
    #pragma unroll
    for (int j = 0; j < 16; ++j) {
      float p = fminf(after + suf[j], 999.0f);
      float fl = floorf(p);
      int fi = (int)fl;
      int ci = (int)ceilf(p);
      float w = p - fl;
      float lf = bf2f(li_s[q][fi]);
      float lc = bf2f(li_s[q][ci]);
      lg[j] = s[j] + lc * w + lf * (1.f - w);
      m = fmaxf(m, lg[j]);
    }
    #pragma unroll
    for (int off = 1; off < 64; off <<= 1) m = fmaxf(m, __shfl_xor(m, off));
    float rs = 0.f;
    us pb[16];
    #pragma unroll
    for (int j = 0; j < 16; ++j) {
      float e = __expf(lg[j] - m);
      rs += e;
      pb[j] = f2bf(e);
    }
    #pragma unroll
    for (int off = 1; off < 64; off <<= 1) rs += __shfl_xor(rs, off);
    us* Pp = &S_s[q][lane * 16];
    #pragma unroll
    for (int j = 0; j < 16; ++j) Pp[j] = pb[j];
    if (lane == 0) qinv_s[q] = 1.0f / rs;
  }
  __syncthreads();

  // ---- Phase D: O = P @ (Vh + Vl)
  f32x4 o = {0.f, 0.f, 0.f, 0.f};
  const int d0 = wv * 16;
  #pragma unroll 4
  for (int kt = 0; kt < 32; ++kt) {
    int t0 = kt * 32;
    short8 a = *(const short8*)&S_s[col][t0 + quad * 8];
    short8 bh = *(const short8*)(Vh + (size_t)(d0 + col) * 1024 + t0 + quad * 8);
    short8 bl = *(const short8*)(Vl + (size_t)(d0 + col) * 1024 + t0 + quad * 8);
    o = MFMA16(a, bh, o, 0, 0, 0);
    o = MFMA16(a, bl, o, 0, 0, 0);
  }
  const int b_ = hb & 3, h = hb >> 2;
  #pragma unroll
  for (int r = 0; r < 4; ++r) {
    int q = quad * 4 + r;
    float val = o[r] * qinv_s[q];
    size_t idx = (size_t)((s0 + q) * 4 + b_) * 1024 + h * 64 + d0 + col;
    us hh, ll; split_bf(val, hh, ll);
    ah[idx] = hh;
    al[idx] = ll;
  }
}

extern "C" void kernel_launch(void* const* d_in, const int* in_sizes, int n_in,
                              void* d_out, int out_size, void* d_ws, size_t ws_size,
                              hipStream_t stream) {
  const float* x  = (const float*)d_in[0];
  const float* Wq = (const float*)d_in[1];
  const float* bq = (const float*)d_in[2];
  const float* Wk = (const float*)d_in[3];
  const float* bk = (const float*)d_in[4];
  const float* Wv = (const float*)d_in[5];
  const float* bv = (const float*)d_in[6];
  const float* Wo = (const float*)d_in[7];
  const float* bo = (const float*)d_in[8];
  const float* pe = (const float*)d_in[9];

  us* w = (us*)d_ws;
  us* xh  = w;                      // 4096x1024
  us* xl  = w + 4194304;
  us* wqk = w + 8388608;            // 2048x1024
  us* wvh = w + 10485760;           // 1024x1024 each
  us* wvl = w + 11534336;
  us* woh = w + 12582912;
  us* wol = w + 13631488;
  us* pet = w + 14680064;           // 1000x64 (padded region)
  us* qb  = w + 14745600;           // 64x1024x64 each
  us* kb  = w + 18939904;
  us* vth = w + 23134208;
  us* vtl = w + 27328512;
  us* ah  = w + 31522816;
  us* al  = w + 35717120;

  prep_k<<<6208, 256, 0, stream>>>(x, Wq, Wk, Wv, Wo, pe,
                                   xh, xl, wqk, wvh, wvl, woh, wol, pet);
  mgemm<1, 128><<<dim3(16, 32), 256, 0, stream>>>(
      xh, nullptr, wqk, nullptr, bq, bk, qb, kb, 0);
  mgemm<3, 64><<<dim3(16, 32), 256, 0, stream>>>(
      xh, xl, wvh, wvl, bv, bv, vth, vtl, 1);
  attn_k<<<dim3(64, 64), 256, 0, stream>>>(qb, kb, vth, vtl, pet, ah, al);
  mgemm<3, 64><<<dim3(16, 32), 256, 0, stream>>>(
      ah, al, woh, wol, bo, bo, (void*)d_out, nullptr, 2);
}

// Round 4
// 473.296 us; speedup vs baseline: 5.8881x; 1.0621x over previous
//
#include <hip/hip_runtime.h>
#include <hip/hip_bf16.h>

#define D_MODEL 1024
#define NHEAD 16
#define HEAD_DIM 64
#define SEQ 1024
#define BATCH 4

typedef unsigned short us;
typedef __attribute__((ext_vector_type(8))) short short8;
typedef __attribute__((ext_vector_type(4))) float f32x4;

#define MFMA16 __builtin_amdgcn_mfma_f32_16x16x32_bf16

__device__ __forceinline__ float sigmoidf_(float x) {
  return 1.0f / (1.0f + __expf(-x));
}
__device__ __forceinline__ us f2bf(float x) {
  union { float f; unsigned u; } v; v.f = x;
  unsigned r = v.u + 0x7fffu + ((v.u >> 16) & 1u);
  return (us)(r >> 16);
}
__device__ __forceinline__ float bf2f(us s) {
  union { unsigned u; float f; } v; v.u = ((unsigned)s) << 16; return v.f;
}
__device__ __forceinline__ void split_bf(float v, us& h, us& l) {
  h = f2bf(v);
  l = f2bf(v - bf2f(h));
}
__device__ __forceinline__ void async16(us* lds, const us* g) {
  __builtin_amdgcn_global_load_lds(
      (const __attribute__((address_space(1))) unsigned int*)(const void*)g,
      (__attribute__((address_space(3))) unsigned int*)(void*)lds, 16, 0, 0);
}

// ---------------- prep: bf16 convert / transpose -----------------------------
__global__ __launch_bounds__(256) void prep_k(
    const float* __restrict__ x, const float* __restrict__ Wq,
    const float* __restrict__ Wk, const float* __restrict__ Wv,
    const float* __restrict__ Wo, const float* __restrict__ pe,
    us* __restrict__ xh, us* __restrict__ xl, us* __restrict__ wqk,
    us* __restrict__ wvh, us* __restrict__ wvl, us* __restrict__ woh,
    us* __restrict__ wol, us* __restrict__ pet)
{
  __shared__ float tile[32][33];
  const int bid = blockIdx.x, tid = threadIdx.x;
  if (bid < 2048) {
    int i0 = bid * 2048 + tid * 8;
    float4 v0 = *(const float4*)(x + i0);
    float4 v1 = *(const float4*)(x + i0 + 4);
    float vv[8] = {v0.x, v0.y, v0.z, v0.w, v1.x, v1.y, v1.z, v1.w};
    short8 hh, ll;
    #pragma unroll
    for (int j = 0; j < 8; ++j) {
      us h, l; split_bf(vv[j], h, l);
      hh[j] = (short)h; ll[j] = (short)l;
    }
    *(short8*)(xh + i0) = hh;
    *(short8*)(xl + i0) = ll;
  } else if (bid < 6144) {
    int wj = bid - 2048;
    int w = wj >> 10, t = wj & 1023;
    int k0 = (t >> 5) * 32, n0 = (t & 31) * 32;
    const float* W = (w == 0) ? Wq : (w == 1) ? Wk : (w == 2) ? Wv : Wo;
    int tx = tid & 31, ty = tid >> 5;
    #pragma unroll
    for (int rep = 0; rep < 4; ++rep) {
      int ky = ty * 4 + rep;
      tile[ky][tx] = W[(size_t)(k0 + ky) * 1024 + n0 + tx];
    }
    __syncthreads();
    #pragma unroll
    for (int rep = 0; rep < 4; ++rep) {
      int ny = ty * 4 + rep;
      float v = tile[tx][ny];
      int n = n0 + ny, k = k0 + tx;
      if (w < 2) {
        wqk[(size_t)(w * 1024 + n) * 1024 + k] = f2bf(v);
      } else {
        us h, l; split_bf(v, h, l);
        us* dh = (w == 2) ? wvh : woh;
        us* dl = (w == 2) ? wvl : wol;
        dh[(size_t)n * 1024 + k] = h;
        dl[(size_t)n * 1024 + k] = l;
      }
    }
  } else {
    int pj = bid - 6144;
    int k0 = (pj & 1) * 32, n0 = (pj >> 1) * 32;
    int tx = tid & 31, ty = tid >> 5;
    #pragma unroll
    for (int rep = 0; rep < 4; ++rep) {
      int ky = ty * 4 + rep;
      tile[ky][tx] = (n0 + tx < 1000) ? pe[(size_t)(k0 + ky) * 1000 + n0 + tx] : 0.f;
    }
    __syncthreads();
    #pragma unroll
    for (int rep = 0; rep < 4; ++rep) {
      int ny = ty * 4 + rep;
      int n = n0 + ny;
      if (n < 1000) pet[(size_t)n * 64 + k0 + tx] = f2bf(tile[tx][ny]);
    }
  }
}

// ---------------- bf16 MFMA GEMM, m97-style ---------------------------------
template<int TERMS, int TN>
__global__ __launch_bounds__(256) void mgemm(
    const us* __restrict__ A0, const us* __restrict__ A1,
    const us* __restrict__ B0, const us* __restrict__ B1,
    const float* __restrict__ bias0, const float* __restrict__ bias1,
    void* out0, void* out1, int mode)
{
  constexpr int PA = (TERMS == 3) ? 2 : 1;
  constexpr int NJ = TN / 32;
  constexpr int NW = TN / 2;
  __shared__ us As[PA][128][32];
  __shared__ us Bs[PA][TN][32];
  const int tid = threadIdx.x, ln = tid & 63, wv = tid >> 6;
  const int col = ln & 15, quad = ln >> 4;
  const int wr = wv >> 1, wc = wv & 1;
  const int m0 = blockIdx.y * 128, n0 = blockIdx.x * TN;
  const us* Ap[2] = {A0, A1};
  const us* Bp[2] = {B0, B1};

  f32x4 acc[4][NJ];
  #pragma unroll
  for (int i = 0; i < 4; ++i)
    #pragma unroll
    for (int j = 0; j < NJ; ++j) acc[i][j] = (f32x4){0.f, 0.f, 0.f, 0.f};

  for (int kt = 0; kt < 1024; kt += 32) {
    #pragma unroll
    for (int p = 0; p < PA; ++p)
      #pragma unroll
      for (int j = 0; j < 2; ++j) {
        int c = j * 256 + wv * 64 + ln;
        int m = c >> 2;
        int kq = (c & 3) ^ ((c >> 3) & 3);
        async16((us*)&As[p][0][0] + (size_t)(j * 256 + wv * 64) * 8,
                Ap[p] + (size_t)(m0 + m) * 1024 + kt + kq * 8);
      }
    #pragma unroll
    for (int p = 0; p < PA; ++p)
      #pragma unroll
      for (int j = 0; j < TN / 64; ++j) {
        int c = j * 256 + wv * 64 + ln;
        int n = c >> 2;
        int kq = (c & 3) ^ ((c >> 3) & 3);
        async16((us*)&Bs[p][0][0] + (size_t)(j * 256 + wv * 64) * 8,
                Bp[p] + (size_t)(n0 + n) * 1024 + kt + kq * 8);
      }
    __syncthreads();

    short8 a0[4], a1[4], b0[NJ], b1[NJ];
    #pragma unroll
    for (int i = 0; i < 4; ++i) {
      int r = wr * 64 + i * 16 + col;
      int q = quad ^ ((r >> 1) & 3);
      a0[i] = *(const short8*)&As[0][r][q * 8];
      if constexpr (TERMS == 3) a1[i] = *(const short8*)&As[1][r][q * 8];
    }
    #pragma unroll
    for (int j = 0; j < NJ; ++j) {
      int r = wc * NW + j * 16 + col;
      int q = quad ^ ((r >> 1) & 3);
      b0[j] = *(const short8*)&Bs[0][r][q * 8];
      if constexpr (TERMS == 3) b1[j] = *(const short8*)&Bs[1][r][q * 8];
    }
    #pragma unroll
    for (int i = 0; i < 4; ++i)
      #pragma unroll
      for (int j = 0; j < NJ; ++j) {
        acc[i][j] = MFMA16(a0[i], b0[j], acc[i][j], 0, 0, 0);
        if constexpr (TERMS == 3) {
          acc[i][j] = MFMA16(a0[i], b1[j], acc[i][j], 0, 0, 0);
          acc[i][j] = MFMA16(a1[i], b0[j], acc[i][j], 0, 0, 0);
        }
      }
    __syncthreads();
  }

  #pragma unroll
  for (int i = 0; i < 4; ++i)
    #pragma unroll
    for (int j = 0; j < NJ; ++j)
      #pragma unroll
      for (int r = 0; r < 4; ++r) {
        int grow = m0 + wr * 64 + i * 16 + quad * 4 + r;
        int gcol = n0 + wc * NW + j * 16 + col;
        float val = acc[i][j][r];
        if (mode == 0) {
          val += (gcol < 1024 ? bias0 : bias1)[gcol & 1023];
          int h = (gcol >> 6) & 15, d = gcol & 63, b = grow & 3, s = grow >> 2;
          ((us*)(gcol < 1024 ? out0 : out1))
              [(size_t)((h * 4 + b) * 1024 + s) * 64 + d] = f2bf(val);
        } else if (mode == 1) {
          val += bias0[gcol];
          int h = gcol >> 6, d = gcol & 63, b = grow & 3, s = grow >> 2;
          size_t idx = (size_t)((h * 4 + b) * 64 + d) * 1024 + s;
          us hh, ll; split_bf(val, hh, ll);
          ((us*)out0)[idx] = hh;
          ((us*)out1)[idx] = ll;
        } else {
          val += bias0[gcol];
          ((float*)out0)[(size_t)grow * 1024 + gcol] = val;
        }
      }
}

// ---------------- MFMA fused CoPE attention, 16 waves/block -----------------
// Block: 16 queries of one (h,b); 1024 threads = 16 waves.
// Phase A/B: wave w covers keys/positions [64w, 64w+64).
// Phase C: wave w owns query w (fully parallel, wave-private).
// Phase D: wave w = (wk,wd): k-quarter wk, d-group wd; LDS reduce over wk.
__global__ __launch_bounds__(1024) void attn_k(
    const us* __restrict__ qb, const us* __restrict__ kb,
    const us* __restrict__ vth, const us* __restrict__ vtl,
    const us* __restrict__ pet, us* __restrict__ ah, us* __restrict__ al)
{
  __shared__ us S_s[16][1032];
  __shared__ alignas(16) us li_s[16][1024];   // reused as f32x4 reduce buf
  __shared__ float qinv_s[16];

  const int tid = threadIdx.x;
  const int lane = tid & 63;
  const int wv = tid >> 6;
  const int col = lane & 15;
  const int quad = lane >> 4;
  const int hb = blockIdx.y;
  const int s0 = blockIdx.x * 16;

  const us* Q = qb + ((size_t)hb * SEQ + s0) * HEAD_DIM;
  const us* K = kb + (size_t)hb * SEQ * HEAD_DIM;
  const us* Vh = vth + (size_t)hb * HEAD_DIM * SEQ;
  const us* Vl = vtl + (size_t)hb * HEAD_DIM * SEQ;

  short8 aq0 = *(const short8*)(Q + col * 64 + quad * 8);
  short8 aq1 = *(const short8*)(Q + col * 64 + 32 + quad * 8);

  // ---- Phase A: scores for keys [64*wv, 64*wv+64)
  #pragma unroll
  for (int kt = 0; kt < 4; ++kt) {
    int t0 = wv * 64 + kt * 16;
    const us* Kr = K + (size_t)(t0 + col) * 64;
    short8 b0 = *(const short8*)(Kr + quad * 8);
    short8 b1 = *(const short8*)(Kr + 32 + quad * 8);
    f32x4 sc = {0.f, 0.f, 0.f, 0.f};
    sc = MFMA16(aq0, b0, sc, 0, 0, 0);
    sc = MFMA16(aq1, b1, sc, 0, 0, 0);
    #pragma unroll
    for (int r = 0; r < 4; ++r)
      S_s[quad * 4 + r][t0 + col] = f2bf(sc[r] * 0.125f);
  }

  // ---- Phase B: interp logits for positions [64*wv, 64*wv+64)
  #pragma unroll
  for (int nt = 0; nt < 4; ++nt) {
    int n = wv * 64 + nt * 16 + col;
    int nn = (n < 1000) ? n : 999;
    short8 b0 = *(const short8*)(pet + (size_t)nn * 64 + quad * 8);
    short8 b1 = *(const short8*)(pet + (size_t)nn * 64 + 32 + quad * 8);
    f32x4 li = {0.f, 0.f, 0.f, 0.f};
    li = MFMA16(aq0, b0, li, 0, 0, 0);
    li = MFMA16(aq1, b1, li, 0, 0, 0);
    #pragma unroll
    for (int r = 0; r < 4; ++r)
      li_s[quad * 4 + r][n] = f2bf(li[r]);
  }
  __syncthreads();

  // ---- Phase C: query wv — reverse cumsum + CoPE + softmax (wave-private)
  {
    const int q = wv;
    const us* Sp = &S_s[q][lane * 16];
    float s[16], suf[16];
    #pragma unroll
    for (int j = 0; j < 16; ++j) s[j] = bf2f(Sp[j]);
    float run = 0.f;
    #pragma unroll
    for (int j = 15; j >= 0; --j) {
      run += sigmoidf_(s[j]);
      suf[j] = run;
    }
    float v = run;
    #pragma unroll
    for (int off = 1; off < 64; off <<= 1) {
      float u = __shfl_down(v, off);
      v += (lane + off < 64) ? u : 0.f;
    }
    float after = v - run;
    float lg[16];
    float m = -1e30f;
    #pragma unroll
    for (int j = 0; j < 16; ++j) {
      float p = fminf(after + suf[j], 999.0f);
      float fl = floorf(p);
      int fi = (int)fl;
      int ci = (int)ceilf(p);
      float w = p - fl;
      float lf = bf2f(li_s[q][fi]);
      float lc = bf2f(li_s[q][ci]);
      lg[j] = s[j] + lc * w + lf * (1.f - w);
      m = fmaxf(m, lg[j]);
    }
    #pragma unroll
    for (int off = 1; off < 64; off <<= 1) m = fmaxf(m, __shfl_xor(m, off));
    float rs = 0.f;
    us* Pp = &S_s[q][lane * 16];
    #pragma unroll
    for (int j = 0; j < 16; ++j) {
      float e = __expf(lg[j] - m);
      rs += e;
      Pp[j] = f2bf(e);
    }
    #pragma unroll
    for (int off = 1; off < 64; off <<= 1) rs += __shfl_xor(rs, off);
    if (lane == 0) qinv_s[q] = 1.0f / rs;
  }
  __syncthreads();

  // ---- Phase D: O partial = P[:, 256*wk..+256] @ V[256*wk..+256, 16*wd..+16]
  const int wk = wv >> 2, wd = wv & 3;
  const int d0 = wd * 16;
  f32x4 o = {0.f, 0.f, 0.f, 0.f};
  #pragma unroll
  for (int kt = 0; kt < 8; ++kt) {
    int t0 = wk * 256 + kt * 32;
    short8 a = *(const short8*)&S_s[col][t0 + quad * 8];
    short8 bh = *(const short8*)(Vh + (size_t)(d0 + col) * 1024 + t0 + quad * 8);
    short8 bl = *(const short8*)(Vl + (size_t)(d0 + col) * 1024 + t0 + quad * 8);
    o = MFMA16(a, bh, o, 0, 0, 0);
    o = MFMA16(a, bl, o, 0, 0, 0);
  }
  __syncthreads();                    // li_s reads done; safe to overlay
  f32x4* red = (f32x4*)&li_s[0][0];   // 16 KB of the 32 KB region
  red[wv * 64 + lane] = o;
  __syncthreads();
  if (wv < 4) {
    f32x4 t0v = red[(0 * 4 + wv) * 64 + lane];
    f32x4 t1v = red[(1 * 4 + wv) * 64 + lane];
    f32x4 t2v = red[(2 * 4 + wv) * 64 + lane];
    f32x4 t3v = red[(3 * 4 + wv) * 64 + lane];
    const int b_ = hb & 3, h = hb >> 2;
    #pragma unroll
    for (int r = 0; r < 4; ++r) {
      int q = quad * 4 + r;
      float val = (t0v[r] + t1v[r] + t2v[r] + t3v[r]) * qinv_s[q];
      size_t idx = (size_t)((s0 + q) * 4 + b_) * 1024 + h * 64 + wv * 16 + col;
      us hh, ll; split_bf(val, hh, ll);
      ah[idx] = hh;
      al[idx] = ll;
    }
  }
}

extern "C" void kernel_launch(void* const* d_in, const int* in_sizes, int n_in,
                              void* d_out, int out_size, void* d_ws, size_t ws_size,
                              hipStream_t stream) {
  const float* x  = (const float*)d_in[0];
  const float* Wq = (const float*)d_in[1];
  const float* bq = (const float*)d_in[2];
  const float* Wk = (const float*)d_in[3];
  const float* bk = (const float*)d_in[4];
  const float* Wv = (const float*)d_in[5];
  const float* bv = (const float*)d_in[6];
  const float* Wo = (const float*)d_in[7];
  const float* bo = (const float*)d_in[8];
  const float* pe = (const float*)d_in[9];

  us* w = (us*)d_ws;
  us* xh  = w;
  us* xl  = w + 4194304;
  us* wqk = w + 8388608;
  us* wvh = w + 10485760;
  us* wvl = w + 11534336;
  us* woh = w + 12582912;
  us* wol = w + 13631488;
  us* pet = w + 14680064;
  us* qb  = w + 14745600;
  us* kb  = w + 18939904;
  us* vth = w + 23134208;
  us* vtl = w + 27328512;
  us* ah  = w + 31522816;
  us* al  = w + 35717120;

  prep_k<<<6208, 256, 0, stream>>>(x, Wq, Wk, Wv, Wo, pe,
                                   xh, xl, wqk, wvh, wvl, woh, wol, pet);
  mgemm<1, 128><<<dim3(16, 32), 256, 0, stream>>>(
      xh, nullptr, wqk, nullptr, bq, bk, qb, kb, 0);
  mgemm<3, 64><<<dim3(16, 32), 256, 0, stream>>>(
      xh, xl, wvh, wvl, bv, bv, vth, vtl, 1);
  attn_k<<<dim3(64, 64), 1024, 0, stream>>>(qb, kb, vth, vtl, pet, ah, al);
  mgemm<3, 64><<<dim3(16, 32), 256, 0, stream>>>(
      ah, al, woh, wol, bo, bo, (void*)d_out, nullptr, 2);
}

// Round 5
// 403.836 us; speedup vs baseline: 6.9008x; 1.1720x over previous
//
#include <hip/hip_runtime.h>
#include <hip/hip_bf16.h>

#define D_MODEL 1024
#define NHEAD 16
#define HEAD_DIM 64
#define SEQ 1024
#define BATCH 4

typedef unsigned short us;
typedef __attribute__((ext_vector_type(8))) short short8;
typedef __attribute__((ext_vector_type(4))) float f32x4;

#define MFMA16 __builtin_amdgcn_mfma_f32_16x16x32_bf16

__device__ __forceinline__ float sigmoidf_(float x) {
  return 1.0f / (1.0f + __expf(-x));
}
__device__ __forceinline__ us f2bf(float x) {
  union { float f; unsigned u; } v; v.f = x;
  unsigned r = v.u + 0x7fffu + ((v.u >> 16) & 1u);
  return (us)(r >> 16);
}
__device__ __forceinline__ float bf2f(us s) {
  union { unsigned u; float f; } v; v.u = ((unsigned)s) << 16; return v.f;
}
__device__ __forceinline__ void split_bf(float v, us& h, us& l) {
  h = f2bf(v);
  l = f2bf(v - bf2f(h));
}
__device__ __forceinline__ void async16(us* lds, const us* g) {
  __builtin_amdgcn_global_load_lds(
      (const __attribute__((address_space(1))) unsigned int*)(const void*)g,
      (__attribute__((address_space(3))) unsigned int*)(void*)lds, 16, 0, 0);
}

// ---------------- prep: bf16 convert / transpose -----------------------------
__global__ __launch_bounds__(256) void prep_k(
    const float* __restrict__ x, const float* __restrict__ Wq,
    const float* __restrict__ Wk, const float* __restrict__ Wv,
    const float* __restrict__ Wo, const float* __restrict__ pe,
    us* __restrict__ xh, us* __restrict__ xl, us* __restrict__ wqk,
    us* __restrict__ wvh, us* __restrict__ wvl, us* __restrict__ woh,
    us* __restrict__ wol, us* __restrict__ pet)
{
  __shared__ float tile[32][33];
  const int bid = blockIdx.x, tid = threadIdx.x;
  if (bid < 2048) {
    int i0 = bid * 2048 + tid * 8;
    float4 v0 = *(const float4*)(x + i0);
    float4 v1 = *(const float4*)(x + i0 + 4);
    float vv[8] = {v0.x, v0.y, v0.z, v0.w, v1.x, v1.y, v1.z, v1.w};
    short8 hh, ll;
    #pragma unroll
    for (int j = 0; j < 8; ++j) {
      us h, l; split_bf(vv[j], h, l);
      hh[j] = (short)h; ll[j] = (short)l;
    }
    *(short8*)(xh + i0) = hh;
    *(short8*)(xl + i0) = ll;
  } else if (bid < 6144) {
    int wj = bid - 2048;
    int w = wj >> 10, t = wj & 1023;
    int k0 = (t >> 5) * 32, n0 = (t & 31) * 32;
    const float* W = (w == 0) ? Wq : (w == 1) ? Wk : (w == 2) ? Wv : Wo;
    int tx = tid & 31, ty = tid >> 5;
    #pragma unroll
    for (int rep = 0; rep < 4; ++rep) {
      int ky = ty * 4 + rep;
      tile[ky][tx] = W[(size_t)(k0 + ky) * 1024 + n0 + tx];
    }
    __syncthreads();
    #pragma unroll
    for (int rep = 0; rep < 4; ++rep) {
      int ny = ty * 4 + rep;
      float v = tile[tx][ny];
      int n = n0 + ny, k = k0 + tx;
      if (w < 2) {
        wqk[(size_t)(w * 1024 + n) * 1024 + k] = f2bf(v);
      } else {
        us h, l; split_bf(v, h, l);
        us* dh = (w == 2) ? wvh : woh;
        us* dl = (w == 2) ? wvl : wol;
        dh[(size_t)n * 1024 + k] = h;
        dl[(size_t)n * 1024 + k] = l;
      }
    }
  } else {
    int pj = bid - 6144;
    int k0 = (pj & 1) * 32, n0 = (pj >> 1) * 32;
    int tx = tid & 31, ty = tid >> 5;
    #pragma unroll
    for (int rep = 0; rep < 4; ++rep) {
      int ky = ty * 4 + rep;
      tile[ky][tx] = (n0 + tx < 1000) ? pe[(size_t)(k0 + ky) * 1000 + n0 + tx] : 0.f;
    }
    __syncthreads();
    #pragma unroll
    for (int rep = 0; rep < 4; ++rep) {
      int ny = ty * 4 + rep;
      int n = n0 + ny;
      if (n < 1000) pet[(size_t)n * 64 + k0 + tx] = f2bf(tile[tx][ny]);
    }
  }
}

// ---------------- bf16 MFMA GEMM, m97-style ---------------------------------
template<int TERMS, int TN>
__global__ __launch_bounds__(256) void mgemm(
    const us* __restrict__ A0, const us* __restrict__ A1,
    const us* __restrict__ B0, const us* __restrict__ B1,
    const float* __restrict__ bias0, const float* __restrict__ bias1,
    void* out0, void* out1, int mode)
{
  constexpr int PA = (TERMS == 3) ? 2 : 1;
  constexpr int NJ = TN / 32;
  constexpr int NW = TN / 2;
  __shared__ us As[PA][128][32];
  __shared__ us Bs[PA][TN][32];
  const int tid = threadIdx.x, ln = tid & 63, wv = tid >> 6;
  const int col = ln & 15, quad = ln >> 4;
  const int wr = wv >> 1, wc = wv & 1;
  const int m0 = blockIdx.y * 128, n0 = blockIdx.x * TN;
  const us* Ap[2] = {A0, A1};
  const us* Bp[2] = {B0, B1};

  f32x4 acc[4][NJ];
  #pragma unroll
  for (int i = 0; i < 4; ++i)
    #pragma unroll
    for (int j = 0; j < NJ; ++j) acc[i][j] = (f32x4){0.f, 0.f, 0.f, 0.f};

  for (int kt = 0; kt < 1024; kt += 32) {
    #pragma unroll
    for (int p = 0; p < PA; ++p)
      #pragma unroll
      for (int j = 0; j < 2; ++j) {
        int c = j * 256 + wv * 64 + ln;
        int m = c >> 2;
        int kq = (c & 3) ^ ((c >> 3) & 3);
        async16((us*)&As[p][0][0] + (size_t)(j * 256 + wv * 64) * 8,
                Ap[p] + (size_t)(m0 + m) * 1024 + kt + kq * 8);
      }
    #pragma unroll
    for (int p = 0; p < PA; ++p)
      #pragma unroll
      for (int j = 0; j < TN / 64; ++j) {
        int c = j * 256 + wv * 64 + ln;
        int n = c >> 2;
        int kq = (c & 3) ^ ((c >> 3) & 3);
        async16((us*)&Bs[p][0][0] + (size_t)(j * 256 + wv * 64) * 8,
                Bp[p] + (size_t)(n0 + n) * 1024 + kt + kq * 8);
      }
    __syncthreads();

    short8 a0[4], a1[4], b0[NJ], b1[NJ];
    #pragma unroll
    for (int i = 0; i < 4; ++i) {
      int r = wr * 64 + i * 16 + col;
      int q = quad ^ ((r >> 1) & 3);
      a0[i] = *(const short8*)&As[0][r][q * 8];
      if constexpr (TERMS == 3) a1[i] = *(const short8*)&As[1][r][q * 8];
    }
    #pragma unroll
    for (int j = 0; j < NJ; ++j) {
      int r = wc * NW + j * 16 + col;
      int q = quad ^ ((r >> 1) & 3);
      b0[j] = *(const short8*)&Bs[0][r][q * 8];
      if constexpr (TERMS == 3) b1[j] = *(const short8*)&Bs[1][r][q * 8];
    }
    #pragma unroll
    for (int i = 0; i < 4; ++i)
      #pragma unroll
      for (int j = 0; j < NJ; ++j) {
        acc[i][j] = MFMA16(a0[i], b0[j], acc[i][j], 0, 0, 0);
        if constexpr (TERMS == 3) {
          acc[i][j] = MFMA16(a0[i], b1[j], acc[i][j], 0, 0, 0);
          acc[i][j] = MFMA16(a1[i], b0[j], acc[i][j], 0, 0, 0);
        }
      }
    __syncthreads();
  }

  #pragma unroll
  for (int i = 0; i < 4; ++i)
    #pragma unroll
    for (int j = 0; j < NJ; ++j)
      #pragma unroll
      for (int r = 0; r < 4; ++r) {
        int grow = m0 + wr * 64 + i * 16 + quad * 4 + r;
        int gcol = n0 + wc * NW + j * 16 + col;
        float val = acc[i][j][r];
        if (mode == 0) {
          val += (gcol < 1024 ? bias0 : bias1)[gcol & 1023];
          int h = (gcol >> 6) & 15, d = gcol & 63, b = grow & 3, s = grow >> 2;
          ((us*)(gcol < 1024 ? out0 : out1))
              [(size_t)((h * 4 + b) * 1024 + s) * 64 + d] = f2bf(val);
        } else if (mode == 1) {
          val += bias0[gcol];
          int h = gcol >> 6, d = gcol & 63, b = grow & 3, s = grow >> 2;
          size_t idx = (size_t)((h * 4 + b) * 64 + d) * 1024 + s;
          ((us*)out0)[idx] = f2bf(val);   // single bf16 V plane
        } else {
          val += bias0[gcol];
          ((float*)out0)[(size_t)grow * 1024 + gcol] = val;
        }
      }
}

// ---------------- MFMA fused CoPE attention, 16 waves/block -----------------
// Flat grid 4096 with XCD swizzle: all 64 s-tiles of one hb land on one XCD.
__global__ __launch_bounds__(1024) void attn_k(
    const us* __restrict__ qb, const us* __restrict__ kb,
    const us* __restrict__ vth, const us* __restrict__ pet,
    us* __restrict__ ah, us* __restrict__ al)
{
  __shared__ us S_s[16][1032];
  __shared__ alignas(16) us li_s[16][1024];   // reused as f32x4 reduce buf
  __shared__ float qinv_s[16];

  const int tid = threadIdx.x;
  const int lane = tid & 63;
  const int wv = tid >> 6;
  const int col = lane & 15;
  const int quad = lane >> 4;
  const int id = blockIdx.x;
  const int hb = ((id >> 3) & 7) * 8 + (id & 7);   // id % 8 == hb % 8 -> same XCD
  const int s0 = (id >> 6) * 16;

  const us* Q = qb + ((size_t)hb * SEQ + s0) * HEAD_DIM;
  const us* K = kb + (size_t)hb * SEQ * HEAD_DIM;
  const us* Vh = vth + (size_t)hb * HEAD_DIM * SEQ;

  short8 aq0 = *(const short8*)(Q + col * 64 + quad * 8);
  short8 aq1 = *(const short8*)(Q + col * 64 + 32 + quad * 8);

  // ---- Phase A: scores for keys [64*wv, 64*wv+64)
  #pragma unroll
  for (int kt = 0; kt < 4; ++kt) {
    int t0 = wv * 64 + kt * 16;
    const us* Kr = K + (size_t)(t0 + col) * 64;
    short8 b0 = *(const short8*)(Kr + quad * 8);
    short8 b1 = *(const short8*)(Kr + 32 + quad * 8);
    f32x4 sc = {0.f, 0.f, 0.f, 0.f};
    sc = MFMA16(aq0, b0, sc, 0, 0, 0);
    sc = MFMA16(aq1, b1, sc, 0, 0, 0);
    #pragma unroll
    for (int r = 0; r < 4; ++r)
      S_s[quad * 4 + r][t0 + col] = f2bf(sc[r] * 0.125f);
  }

  // ---- Phase B: interp logits for positions [64*wv, 64*wv+64)
  #pragma unroll
  for (int nt = 0; nt < 4; ++nt) {
    int n = wv * 64 + nt * 16 + col;
    int nn = (n < 1000) ? n : 999;
    short8 b0 = *(const short8*)(pet + (size_t)nn * 64 + quad * 8);
    short8 b1 = *(const short8*)(pet + (size_t)nn * 64 + 32 + quad * 8);
    f32x4 li = {0.f, 0.f, 0.f, 0.f};
    li = MFMA16(aq0, b0, li, 0, 0, 0);
    li = MFMA16(aq1, b1, li, 0, 0, 0);
    #pragma unroll
    for (int r = 0; r < 4; ++r)
      li_s[quad * 4 + r][n] = f2bf(li[r]);
  }
  __syncthreads();

  // ---- Phase C: query wv — reverse cumsum + CoPE + softmax (wave-private)
  {
    const int q = wv;
    short8 s8a = *(const short8*)&S_s[q][lane * 16];
    short8 s8b = *(const short8*)&S_s[q][lane * 16 + 8];
    float s[16], suf[16];
    #pragma unroll
    for (int j = 0; j < 8; ++j) s[j] = bf2f((us)s8a[j]);
    #pragma unroll
    for (int j = 0; j < 8; ++j) s[8 + j] = bf2f((us)s8b[j]);
    float run = 0.f;
    #pragma unroll
    for (int j = 15; j >= 0; --j) {
      run += sigmoidf_(s[j]);
      suf[j] = run;
    }
    float v = run;
    #pragma unroll
    for (int off = 1; off < 64; off <<= 1) {
      float u = __shfl_down(v, off);
      v += (lane + off < 64) ? u : 0.f;
    }
    float after = v - run;
    float lg[16];
    float m = -1e30f;
    #pragma unroll
    for (int j = 0; j < 16; ++j) {
      float p = fminf(after + suf[j], 999.0f);
      float fl = floorf(p);
      int fi = (int)fl;
      int ci = (int)ceilf(p);
      float w = p - fl;
      float lf = bf2f(li_s[q][fi]);
      float lc = bf2f(li_s[q][ci]);
      lg[j] = s[j] + lc * w + lf * (1.f - w);
      m = fmaxf(m, lg[j]);
    }
    #pragma unroll
    for (int off = 1; off < 64; off <<= 1) m = fmaxf(m, __shfl_xor(m, off));
    float rs = 0.f;
    short8 p8a, p8b;
    #pragma unroll
    for (int j = 0; j < 8; ++j) {
      float e = __expf(lg[j] - m);
      rs += e;
      p8a[j] = (short)f2bf(e);
    }
    #pragma unroll
    for (int j = 0; j < 8; ++j) {
      float e = __expf(lg[8 + j] - m);
      rs += e;
      p8b[j] = (short)f2bf(e);
    }
    #pragma unroll
    for (int off = 1; off < 64; off <<= 1) rs += __shfl_xor(rs, off);
    *(short8*)&S_s[q][lane * 16] = p8a;
    *(short8*)&S_s[q][lane * 16 + 8] = p8b;
    if (lane == 0) qinv_s[q] = 1.0f / rs;
  }
  __syncthreads();

  // ---- Phase D: O partial = P[:, 256*wk..+256] @ V[256*wk..+256, 16*wd..+16]
  const int wk = wv >> 2, wd = wv & 3;
  const int d0 = wd * 16;
  f32x4 o = {0.f, 0.f, 0.f, 0.f};
  #pragma unroll
  for (int kt = 0; kt < 8; ++kt) {
    int t0 = wk * 256 + kt * 32;
    short8 a = *(const short8*)&S_s[col][t0 + quad * 8];
    short8 bh = *(const short8*)(Vh + (size_t)(d0 + col) * 1024 + t0 + quad * 8);
    o = MFMA16(a, bh, o, 0, 0, 0);
  }
  __syncthreads();                    // li_s reads done; safe to overlay
  f32x4* red = (f32x4*)&li_s[0][0];
  red[wv * 64 + lane] = o;
  __syncthreads();
  if (wv < 4) {
    f32x4 t0v = red[(0 * 4 + wv) * 64 + lane];
    f32x4 t1v = red[(1 * 4 + wv) * 64 + lane];
    f32x4 t2v = red[(2 * 4 + wv) * 64 + lane];
    f32x4 t3v = red[(3 * 4 + wv) * 64 + lane];
    const int b_ = hb & 3, h = hb >> 2;
    #pragma unroll
    for (int r = 0; r < 4; ++r) {
      int q = quad * 4 + r;
      float val = (t0v[r] + t1v[r] + t2v[r] + t3v[r]) * qinv_s[q];
      size_t idx = (size_t)((s0 + q) * 4 + b_) * 1024 + h * 64 + wv * 16 + col;
      us hh, ll; split_bf(val, hh, ll);
      ah[idx] = hh;
      al[idx] = ll;
    }
  }
}

extern "C" void kernel_launch(void* const* d_in, const int* in_sizes, int n_in,
                              void* d_out, int out_size, void* d_ws, size_t ws_size,
                              hipStream_t stream) {
  const float* x  = (const float*)d_in[0];
  const float* Wq = (const float*)d_in[1];
  const float* bq = (const float*)d_in[2];
  const float* Wk = (const float*)d_in[3];
  const float* bk = (const float*)d_in[4];
  const float* Wv = (const float*)d_in[5];
  const float* bv = (const float*)d_in[6];
  const float* Wo = (const float*)d_in[7];
  const float* bo = (const float*)d_in[8];
  const float* pe = (const float*)d_in[9];

  us* w = (us*)d_ws;
  us* xh  = w;
  us* xl  = w + 4194304;
  us* wqk = w + 8388608;
  us* wvh = w + 10485760;
  us* wvl = w + 11534336;
  us* woh = w + 12582912;
  us* wol = w + 13631488;
  us* pet = w + 14680064;
  us* qb  = w + 14745600;
  us* kb  = w + 18939904;
  us* vth = w + 23134208;
  us* ah  = w + 31522816;
  us* al  = w + 35717120;

  prep_k<<<6208, 256, 0, stream>>>(x, Wq, Wk, Wv, Wo, pe,
                                   xh, xl, wqk, wvh, wvl, woh, wol, pet);
  mgemm<1, 128><<<dim3(16, 32), 256, 0, stream>>>(
      xh, nullptr, wqk, nullptr, bq, bk, qb, kb, 0);
  mgemm<3, 64><<<dim3(16, 32), 256, 0, stream>>>(
      xh, xl, wvh, wvl, bv, bv, vth, nullptr, 1);
  attn_k<<<dim3(4096), 1024, 0, stream>>>(qb, kb, vth, pet, ah, al);
  mgemm<3, 64><<<dim3(16, 32), 256, 0, stream>>>(
      ah, al, woh, wol, bo, bo, (void*)d_out, nullptr, 2);
}